// Round 10
// baseline (474.570 us; speedup 1.0000x reference)
//
#include <hip/hip_runtime.h>

#define B_SZ 2048
#define T_SZ 2048

using f32x16 = float __attribute__((ext_vector_type(16)));

// DPP move: result[lane] = src[perm(lane)] (quad_perm / row_ror patterns; all HW-proven)
template<int CTRL>
__device__ __forceinline__ float dppf(float v) {
  int r = __builtin_amdgcn_update_dpp(0, __builtin_bit_cast(int, v), CTRL, 0xf, 0xf, true);
  return __builtin_bit_cast(float, r);
}

#if __has_builtin(__builtin_amdgcn_make_buffer_rsrc) && __has_builtin(__builtin_amdgcn_raw_ptr_buffer_store_f32)
#define HAVE_BUFSTORE 1
#else
#define HAVE_BUFSTORE 0
#endif

// 4 batch rows per wave: 16-lane group = row; lane owns units sl,sl+16,sl+32,sl+48.
// All-scalar step math (no splats on the chain); reduction = 4 parallel scalar
// channels through a 4-stage DPP butterfly; tanh tail folded into C - 2R.
__global__ __launch_bounds__(256, 1) void sss_kernel(
    const float* __restrict__ x0p, const float* __restrict__ up,
    const float* __restrict__ tfp, const float* __restrict__ thp,
    const float* __restrict__ tup, const float* __restrict__ typ,
    const float* __restrict__ W1p, const float* __restrict__ b1p,
    const float* __restrict__ W2p, const float* __restrict__ Whp,
    float* __restrict__ outp)
{
  const int lane = threadIdx.x & 63;
  const int wv   = __builtin_amdgcn_readfirstlane((int)(threadIdx.x >> 6));
  const int grp  = lane >> 4;              // 16-lane group = row within wave
  const int sl   = lane & 15;              // sub-lane within group
  const int b    = blockIdx.x * 16 + wv * 4 + grp;   // batch row

  // ---- prologue ----
  // fold K = 2*log2(e) into W1/cc: tanh(a) = 1 - 2*rcp(exp2(K*a)+1)
  const float K = 2.8853900817779268f;
  float w1_[4][6], cc[4];
#pragma unroll
  for (int i = 0; i < 4; ++i) {
    const int u = sl + 16 * i;
#pragma unroll
    for (int r = 0; r < 6; ++r) w1_[i][r] = W1p[r * 64 + u] * K;
    float t = b1p[u];
#pragma unroll
    for (int q = 0; q < 5; ++q) t = fmaf(tfp[q], W1p[(6 + q) * 64 + u], t);
    cc[i] = t * K;
  }

  const float scale = tup[0] / typ[0];
  // w2t[k][i] = scale * W2[sl+16i][k]
  float w2t[4][4];
#pragma unroll
  for (int i = 0; i < 4; ++i) {
    const float4 w2r = ((const float4*)W2p)[sl + 16 * i];
    w2t[0][i] = w2r.x * scale;
    w2t[1][i] = w2r.y * scale;
    w2t[2][i] = w2r.z * scale;
    w2t[3][i] = w2r.w * scale;
  }

  // C_k = sum over all 64 units of w2t (loop-invariant): per-lane partial + butterfly
  float C0 = (w2t[0][0] + w2t[0][1]) + (w2t[0][2] + w2t[0][3]);
  float C1 = (w2t[1][0] + w2t[1][1]) + (w2t[1][2] + w2t[1][3]);
  float C2 = (w2t[2][0] + w2t[2][1]) + (w2t[2][2] + w2t[2][3]);
  float C3 = (w2t[3][0] + w2t[3][1]) + (w2t[3][2] + w2t[3][3]);
  C0 += dppf<0xB1>(C0);  C1 += dppf<0xB1>(C1);  C2 += dppf<0xB1>(C2);  C3 += dppf<0xB1>(C3);
  C0 += dppf<0x4E>(C0);  C1 += dppf<0x4E>(C1);  C2 += dppf<0x4E>(C2);  C3 += dppf<0x4E>(C3);
  C0 += dppf<0x124>(C0); C1 += dppf<0x124>(C1); C2 += dppf<0x124>(C2); C3 += dppf<0x124>(C3);
  C0 += dppf<0x128>(C0); C1 += dppf<0x128>(C1); C2 += dppf<0x128>(C2); C3 += dppf<0x128>(C3);

  const float wh0 = Whp[0], wh1 = Whp[1], wh2 = Whp[2], wh3 = Whp[3];
  const float th  = thp[0];

  // per-lane local state: all 4 components scalar
  float x0 = x0p[b * 4 + 0];
  float x1 = x0p[b * 4 + 1];
  float x2 = x0p[b * 4 + 2];
  float x3 = x0p[b * 4 + 3];
  float xC0 = x0 + C0, xC1 = x1 + C1, xC2 = x2 + C2, xC3 = x3 + C3;

  // y0 = h(x_0), UNCLAMPED (matches reference)
  float yv = fmaf(x0, wh0, fmaf(x1, wh1, fmaf(x2, wh2, fmaf(x3, wh3, th))));

  // ---- per-step output store setup ----
  // per group: sub-lanes 0-3 -> outx[b][t][sl]; sub-lane 4 -> outy[b][t]
  const bool s1 = sl & 1;
  const bool s2 = sl & 2;
  const bool is4 = (sl == 4);
  unsigned voff, vinc;
  if (sl < 4) {
    voff = (unsigned)(b * (T_SZ * 4) + sl) * 4u;
    vinc = 16u;
  } else if (sl == 4) {
    voff = (unsigned)((unsigned)B_SZ * T_SZ * 4u + (unsigned)b * T_SZ) * 4u;
    vinc = 4u;
  } else {
    voff = 0xE0000000u;   // permanently out-of-bounds -> HW drops the store
    vinc = 0u;
  }
#if HAVE_BUFSTORE
  const auto rsrc = __builtin_amdgcn_make_buffer_rsrc(
      (void*)outp, (short)0, (int)(B_SZ * (size_t)T_SZ * 5 * 4), 0x00020000);
#else
  const bool doSt = (sl < 5);
  char* outB = (char*)outp;
#endif

  const f32x16* up16 = (const f32x16*)(up + (size_t)b * (T_SZ * 2)); // 8 steps/chunk
  f32x16 uch = up16[0];
  const int NC = T_SZ / 8;

  for (int c = 0; c < NC; ++c) {
    const int g = (c + 1 < NC) ? c + 1 : NC - 1;   // prefetch next chunk
    const f32x16 unx = up16[g];
#pragma unroll
    for (int jj = 0; jj < 8; ++jj) {
      // ---- emit PRE-update carry (x_step, y_step); exec-free when bufstore ----
      const float vlow  = s1 ? x1 : x0;
      const float vhigh = s1 ? x3 : x2;
      const float vx    = s2 ? vhigh : vlow;
      const float vdata = is4 ? yv : vx;
#if HAVE_BUFSTORE
      __builtin_amdgcn_raw_ptr_buffer_store_f32(vdata, rsrc, (int)voff, 0, 0);
#else
      if (doSt) *(float*)(outB + voff) = vdata;
#endif
      voff += vinc;

      const float u0 = uch[2 * jj];
      const float u1 = uch[2 * jj + 1];

      // pre-activation + r = rcp(exp2(acc)+1), 4 units (scalar, no splats)
      float r_[4];
#pragma unroll
      for (int i = 0; i < 4; ++i) {
        const float base = fmaf(u1, w1_[i][5], fmaf(u0, w1_[i][4], cc[i]));
        const float m23  = fmaf(x2, w1_[i][2], x3 * w1_[i][3]);  // x3 unclipped: ready first
        const float m01  = fmaf(x1, w1_[i][1], x0 * w1_[i][0]);
        const float acc  = (base + m23) + m01;
        const float e    = __builtin_amdgcn_exp2f(acc);
        r_[i] = __builtin_amdgcn_rcpf(e + 1.0f);
      }

      // R_k = sum r_i * w2t[k][i] (depth-3 trees, 4 parallel channels)
      float R0 = fmaf(r_[1], w2t[0][1], r_[0] * w2t[0][0]) + fmaf(r_[3], w2t[0][3], r_[2] * w2t[0][2]);
      float R1 = fmaf(r_[1], w2t[1][1], r_[0] * w2t[1][0]) + fmaf(r_[3], w2t[1][3], r_[2] * w2t[1][2]);
      float R2 = fmaf(r_[1], w2t[2][1], r_[0] * w2t[2][0]) + fmaf(r_[3], w2t[2][3], r_[2] * w2t[2][2]);
      float R3 = fmaf(r_[1], w2t[3][1], r_[0] * w2t[3][0]) + fmaf(r_[3], w2t[3][3], r_[2] * w2t[3][2]);

      // 16-lane all-reduce butterfly, 4 channels interleaved (spaces DPP hazards)
      R0 += dppf<0xB1>(R0);  R1 += dppf<0xB1>(R1);  R2 += dppf<0xB1>(R2);  R3 += dppf<0xB1>(R3);
      R0 += dppf<0x4E>(R0);  R1 += dppf<0x4E>(R1);  R2 += dppf<0x4E>(R2);  R3 += dppf<0x4E>(R3);
      R0 += dppf<0x124>(R0); R1 += dppf<0x124>(R1); R2 += dppf<0x124>(R2); R3 += dppf<0x124>(R3);
      R0 += dppf<0x128>(R0); R1 += dppf<0x128>(R1); R2 += dppf<0x128>(R2); R3 += dppf<0x128>(R3);

      // w_k = x_k + (C_k - 2 R_k) = fma(-2, R_k, xC_k): pre-clip x_raw
      const float wr0 = fmaf(-2.0f, R0, xC0);
      const float wr1 = fmaf(-2.0f, R1, xC1);
      const float wr2 = fmaf(-2.0f, R2, xC2);
      const float wr3 = fmaf(-2.0f, R3, xC3);

      // y from PRE-clip state (off-chain: consumed only by next step's store)
      const float yy = fmaf(wr0, wh0, fmaf(wr1, wh1, fmaf(wr2, wh2, wr3 * wh3)));
      yv = __builtin_amdgcn_fmed3f(yy + th, 0.0f, 10.0f);

      // clip: channels 0..2 -> [0,10], channel 3 unbounded
      x0 = __builtin_amdgcn_fmed3f(wr0, 0.0f, 10.0f);
      x1 = __builtin_amdgcn_fmed3f(wr1, 0.0f, 10.0f);
      x2 = __builtin_amdgcn_fmed3f(wr2, 0.0f, 10.0f);
      x3 = wr3;
      xC0 = x0 + C0; xC1 = x1 + C1; xC2 = x2 + C2; xC3 = x3 + C3;  // off-chain branch
    }
    uch = unx;
  }
}

extern "C" void kernel_launch(void* const* d_in, const int* in_sizes, int n_in,
                              void* d_out, int out_size, void* d_ws, size_t ws_size,
                              hipStream_t stream) {
  (void)in_sizes; (void)n_in; (void)out_size; (void)d_ws; (void)ws_size;
  sss_kernel<<<dim3(B_SZ / 16), dim3(256), 0, stream>>>(
      (const float*)d_in[0], (const float*)d_in[1], (const float*)d_in[2],
      (const float*)d_in[3], (const float*)d_in[4], (const float*)d_in[5],
      (const float*)d_in[6], (const float*)d_in[7], (const float*)d_in[8],
      (const float*)d_in[9], (float*)d_out);
}